// Round 15
// baseline (76.284 us; speedup 1.0000x reference)
//
#include <hip/hip_runtime.h>
#include <math.h>

#define NL 6
#define DD 128

typedef __bf16 bf16x8 __attribute__((ext_vector_type(8)));
typedef float  f32x4  __attribute__((ext_vector_type(4)));

// Frag file per (layer l, net p), base = (l*2+p)*NET_STRIDE (bytes):
//   [0,2048)    trunk A: 2 K-slices x (64 lanes x 16B)
//   [2048,5120) hidden A: 3 x (64 x 16B)   (slots e>=4 zero)
//   [5120,9216) head  A: 4 chunks x (64 x 16B) (slots e>=4 zero)
// Slot map (consistent in A and B, so internal order cancels):
//   slot(q,e) -> logical k = (e<4) ? 4q+e : 16+4q+(e-4)
#define NET_STRIDE 9216
#define OFF_HID    2048
#define OFF_HEAD   5120

static __device__ __forceinline__ unsigned cvt_pk_bf16(float lo, float hi){
    unsigned r;
    asm("v_cvt_pk_bf16_f32 %0, %1, %2" : "=v"(r) : "v"(lo), "v"(hi));
    return r;
}
static __device__ __forceinline__ f32x4 mfma(bf16x8 a, bf16x8 b, f32x4 c){
    return __builtin_amdgcn_mfma_f32_16x16x32_bf16(a, b, c, 0, 0, 0);
}
static __device__ __forceinline__ bf16x8 frag4(unsigned w0, unsigned w1, unsigned w2, unsigned w3){
    int4 v; v.x=(int)w0; v.y=(int)w1; v.z=(int)w2; v.w=(int)w3;
    return __builtin_bit_cast(bf16x8, v);
}
// relu(D regs) -> B-frag for K=16 layers. D feat = 4q+r matches B slot k=4q+e directly.
static __device__ __forceinline__ bf16x8 dreg_to_B(f32x4 d){
    unsigned w0 = cvt_pk_bf16(fmaxf(d[0],0.f), fmaxf(d[1],0.f));
    unsigned w1 = cvt_pk_bf16(fmaxf(d[2],0.f), fmaxf(d[3],0.f));
    return frag4(w0, w1, 0u, 0u);
}
static __device__ __forceinline__ bf16x8 load_frag(const unsigned char* nb, int off, int lane){
    return *(const bf16x8*)(nb + off + lane * 16);
}
// epilogue (r13-proven): y = (xp - t)*e^z, z = 2*rcp(e^{2s}+1)-1 = -tanh(s)
static __device__ __forceinline__ void epi(f32x4 tD, f32x4 sD,
                                           float4 &xa, float4 &xp, float &zacc){
    float xq[4] = {xp.x, xp.y, xp.z, xp.w};
    float nv[4];
    #pragma unroll
    for (int r = 0; r < 4; ++r){
        float u  = exp2f(sD[r] * 2.885390081777927f);      // e^{2s} (sat inf/0, safe)
        float rr = __builtin_amdgcn_rcpf(u + 1.f);
        float z  = fmaf(2.f, rr, -1.f);                    // -tanh(s) in [-1,1]
        float p  = fmaf(0.0086868208f, z, 0.0437939232f);  // e^z, deg-5 poly
        p = fmaf(p, z, 0.1664888732f);
        p = fmaf(p, z, 0.4991967560f);
        p = fmaf(p, z, 1.0000222901f);
        p = fmaf(p, z, 1.0000447786f);
        zacc += z;
        nv[r] = (xq[r] - tD[r]) * p;
    }
    xp = xa;
    xa = (float4){nv[0], nv[1], nv[2], nv[3]};
}

// ---------- pack kernel (byte-identical to round 13) ----------
static __device__ __forceinline__ unsigned short f2bf_rne(float f){
    unsigned u = __float_as_uint(f);
    u += 0x7FFFu + ((u >> 16) & 1u);
    return (unsigned short)(u >> 16);
}

__global__ void pack_frags(
    const float* __restrict__ tW1, const float* __restrict__ tW2,
    const float* __restrict__ tW3, const float* __restrict__ tW4,
    const float* __restrict__ tW5,
    const float* __restrict__ sW1, const float* __restrict__ sW2,
    const float* __restrict__ sW3, const float* __restrict__ sW4,
    const float* __restrict__ sW5,
    unsigned char* __restrict__ pw)
{
    const int bx = blockIdx.x;           // = l*2 + p
    const int l = bx >> 1, p = bx & 1;
    const int aOff = (l & 1) ? 0 : 64;
    const int pOff = 64 - aOff;
    const float* W1 = p ? sW1 : tW1;
    const float* W2 = p ? sW2 : tW2;
    const float* W3 = p ? sW3 : tW3;
    const float* W4 = p ? sW4 : tW4;
    const float* W5 = p ? sW5 : tW5;
    unsigned char* base = pw + (size_t)bx * NET_STRIDE;

    for (int t = threadIdx.x; t < 576; t += blockDim.x){
        const int lane = t & 63, m = lane & 15, q = lane >> 4;
        unsigned short v[8];
        unsigned char* dst;
        if (t < 128){                    // trunk: full K=32 slices
            int slice = t >> 6;
            #pragma unroll
            for (int e = 0; e < 8; ++e){
                int sg = (e < 4) ? (4*q + e) : (16 + 4*q + (e - 4));
                v[e] = f2bf_rne(W1[l*2048 + (aOff + 32*slice + sg)*16 + m]);
            }
            dst = base + slice*1024 + lane*16;
        } else if (t < 320){             // hidden: K=16 in slots e<4, zeros above
            int hh = (t - 128) >> 6;
            const float* W = (hh == 0) ? W2 : (hh == 1) ? W3 : W4;
            #pragma unroll
            for (int e = 0; e < 8; ++e)
                v[e] = (e < 4) ? f2bf_rne(W[l*256 + (4*q + e)*16 + m]) : (unsigned short)0;
            dst = base + OFF_HID + hh*1024 + lane*16;
        } else {                         // head chunk c: passive feats pOff+16c+m
            int c = (t - 320) >> 6;
            #pragma unroll
            for (int e = 0; e < 8; ++e)
                v[e] = (e < 4) ? f2bf_rne(W5[l*2048 + (4*q + e)*128 + pOff + 16*c + m])
                               : (unsigned short)0;
            dst = base + OFF_HEAD + c*1024 + lane*16;
        }
        int4 o;
        o.x = (int)((unsigned)v[0] | ((unsigned)v[1] << 16));
        o.y = (int)((unsigned)v[2] | ((unsigned)v[3] << 16));
        o.z = (int)((unsigned)v[4] | ((unsigned)v[5] << 16));
        o.w = (int)((unsigned)v[6] | ((unsigned)v[7] << 16));
        *(int4*)dst = o;
    }
}

// ---------- main: r13 + register-rotated prefetch of next layer's trunk operands ----------
__global__ __launch_bounds__(256, 4)
void realnvp_mfma16p(const float* __restrict__ X, const unsigned char* __restrict__ PW,
    const float* __restrict__ tb1, const float* __restrict__ tb2,
    const float* __restrict__ tb3, const float* __restrict__ tb4,
    const float* __restrict__ tb5,
    const float* __restrict__ sb1, const float* __restrict__ sb2,
    const float* __restrict__ sb3, const float* __restrict__ sb4,
    const float* __restrict__ sb5,
    float* __restrict__ Y, float* __restrict__ LD, int B)
{
    __shared__ float4 xpl[8][256];       // passive halves, tile0 in [0:4), tile1 in [4:8)
    const int tid  = threadIdx.x;
    const int lane = tid & 63;
    const int wid  = blockIdx.x * 4 + (tid >> 6);
    const int q = lane >> 4, n = lane & 15;
    const int r0 = wid * 32 + n;
    const int r1 = r0 + 16;
    if (wid * 32 >= B) return;
    const int r0c = (r0 < B) ? r0 : (B - 1);
    const int r1c = (r1 < B) ? r1 : (B - 1);

    const float* x0 = X + (size_t)r0c * DD;
    const float* x1 = X + (size_t)r1c * DD;
    float4 xa0[4], xa1[4];
    #pragma unroll
    for (int j = 0; j < 4; ++j){
        const int off = 16*j + 4*q;
        xa0[j]          = *(const float4*)(x0 + off);
        xpl[j][tid]     = *(const float4*)(x0 + 64 + off);
        xa1[j]          = *(const float4*)(x1 + off);
        xpl[4 + j][tid] = *(const float4*)(x1 + 64 + off);
    }
    float zacc0 = 0.f, zacc1 = 0.f;

    // prefetch trunk operands for first processed layer (l = 5)
    bf16x8 A0t, A1t, A0s, A1s;
    f32x4 cbt, cbs;
    {
        const unsigned char* pbt = PW + (size_t)(5 * 2) * NET_STRIDE;
        const unsigned char* pbs = pbt + NET_STRIDE;
        A0t = load_frag(pbt, 0, lane); A1t = load_frag(pbt, 1024, lane);
        A0s = load_frag(pbs, 0, lane); A1s = load_frag(pbs, 1024, lane);
        cbt = *(const f32x4*)(tb1 + 5*16 + 4*q);
        cbs = *(const f32x4*)(sb1 + 5*16 + 4*q);
    }

    #pragma unroll 1
    for (int step = 0; step < NL; ++step){
        const int l = NL - 1 - step;
        const int pOff = (l & 1) ? 64 : 0;
        const unsigned char* bt = PW + (size_t)(l * 2 + 0) * NET_STRIDE;
        const unsigned char* bs = bt + NET_STRIDE;

        // ---- trunk B-frags (per tile) ----
        bf16x8 B00 = frag4(cvt_pk_bf16(xa0[0].x, xa0[0].y), cvt_pk_bf16(xa0[0].z, xa0[0].w),
                           cvt_pk_bf16(xa0[1].x, xa0[1].y), cvt_pk_bf16(xa0[1].z, xa0[1].w));
        bf16x8 B01 = frag4(cvt_pk_bf16(xa0[2].x, xa0[2].y), cvt_pk_bf16(xa0[2].z, xa0[2].w),
                           cvt_pk_bf16(xa0[3].x, xa0[3].y), cvt_pk_bf16(xa0[3].z, xa0[3].w));
        bf16x8 B10 = frag4(cvt_pk_bf16(xa1[0].x, xa1[0].y), cvt_pk_bf16(xa1[0].z, xa1[0].w),
                           cvt_pk_bf16(xa1[1].x, xa1[1].y), cvt_pk_bf16(xa1[1].z, xa1[1].w));
        bf16x8 B11 = frag4(cvt_pk_bf16(xa1[2].x, xa1[2].y), cvt_pk_bf16(xa1[2].z, xa1[2].w),
                           cvt_pk_bf16(xa1[3].x, xa1[3].y), cvt_pk_bf16(xa1[3].z, xa1[3].w));

        // ---- trunk MFMAs with held (prefetched) operands ----
        f32x4 at0 = mfma(A0t, B00, cbt); at0 = mfma(A1t, B01, at0);
        f32x4 at1 = mfma(A0t, B10, cbt); at1 = mfma(A1t, B11, at1);
        f32x4 as0 = mfma(A0s, B00, cbs); as0 = mfma(A1s, B01, as0);
        f32x4 as1 = mfma(A0s, B10, cbs); as1 = mfma(A1s, B11, as1);

        // ---- prefetch NEXT layer's trunk operands (a full layer of compute to hide under) ----
        if (step < NL - 1){
            const unsigned char* nbt = bt - 2 * NET_STRIDE;   // layer l-1, t net
            const unsigned char* nbs = nbt + NET_STRIDE;
            A0t = load_frag(nbt, 0, lane); A1t = load_frag(nbt, 1024, lane);
            A0s = load_frag(nbs, 0, lane); A1s = load_frag(nbs, 1024, lane);
            cbt = *(const f32x4*)(tb1 + (l-1)*16 + 4*q);
            cbs = *(const f32x4*)(sb1 + (l-1)*16 + 4*q);
        }

        // ---- 3 hidden 16x16 layers ----
        #pragma unroll
        for (int hh = 0; hh < 3; ++hh){
            const float* hbt = (hh == 0) ? tb2 : (hh == 1) ? tb3 : tb4;
            const float* hbs = (hh == 0) ? sb2 : (hh == 1) ? sb3 : sb4;
            f32x4 ct = *(const f32x4*)(hbt + l*16 + 4*q);
            f32x4 cs = *(const f32x4*)(hbs + l*16 + 4*q);
            bf16x8 At = load_frag(bt, OFF_HID + hh*1024, lane);
            bf16x8 As = load_frag(bs, OFF_HID + hh*1024, lane);
            at0 = mfma(At, dreg_to_B(at0), ct);
            at1 = mfma(At, dreg_to_B(at1), ct);
            as0 = mfma(As, dreg_to_B(as0), cs);
            as1 = mfma(As, dreg_to_B(as1), cs);
        }

        // ---- heads: 4 chunks of 16 passive feats, chunk-serial ----
        bf16x8 Bf_t0 = dreg_to_B(at0), Bf_t1 = dreg_to_B(at1);
        bf16x8 Bf_s0 = dreg_to_B(as0), Bf_s1 = dreg_to_B(as1);
        #pragma unroll
        for (int c = 0; c < 4; ++c){
            f32x4 ct = *(const f32x4*)(tb5 + l*128 + pOff + 16*c + 4*q);
            f32x4 cs = *(const f32x4*)(sb5 + l*128 + pOff + 16*c + 4*q);
            bf16x8 Aht = load_frag(bt, OFF_HEAD + c*1024, lane);
            bf16x8 Ahs = load_frag(bs, OFF_HEAD + c*1024, lane);
            f32x4 tD0 = mfma(Aht, Bf_t0, ct);
            f32x4 sD0 = mfma(Ahs, Bf_s0, cs);
            f32x4 tD1 = mfma(Aht, Bf_t1, ct);
            f32x4 sD1 = mfma(Ahs, Bf_s1, cs);

            float4 xp0 = xpl[c][tid];
            epi(tD0, sD0, xa0[c], xp0, zacc0);
            xpl[c][tid] = xp0;

            float4 xp1 = xpl[4 + c][tid];
            epi(tD1, sD1, xa1[c], xp1, zacc1);
            xpl[4 + c][tid] = xp1;
        }
    }

    // final: xa = feats [0,64), xpl = feats [64,128);  LD = +sum(z) = -sum(tanh s)
    if (r0 < B){
        float* y0 = Y + (size_t)r0 * DD;
        #pragma unroll
        for (int j = 0; j < 4; ++j){
            const int off = 16*j + 4*q;
            *(float4*)(y0 + off)      = xa0[j];
            *(float4*)(y0 + 64 + off) = xpl[j][tid];
        }
        float ls = zacc0;
        ls += __shfl_xor(ls, 16, 64);
        ls += __shfl_xor(ls, 32, 64);
        if (q == 0) LD[r0] = ls;
    }
    if (r1 < B){
        float* y1 = Y + (size_t)r1 * DD;
        #pragma unroll
        for (int j = 0; j < 4; ++j){
            const int off = 16*j + 4*q;
            *(float4*)(y1 + off)      = xa1[j];
            *(float4*)(y1 + 64 + off) = xpl[4 + j][tid];
        }
        float ls = zacc1;
        ls += __shfl_xor(ls, 16, 64);
        ls += __shfl_xor(ls, 32, 64);
        if (q == 0) LD[r1] = ls;
    }
}

extern "C" void kernel_launch(void* const* d_in, const int* in_sizes, int n_in,
                              void* d_out, int out_size, void* d_ws, size_t ws_size,
                              hipStream_t stream)
{
    const float* X   = (const float*)d_in[0];
    const float* tW1 = (const float*)d_in[2];  const float* tb1 = (const float*)d_in[3];
    const float* tW2 = (const float*)d_in[4];  const float* tb2 = (const float*)d_in[5];
    const float* tW3 = (const float*)d_in[6];  const float* tb3 = (const float*)d_in[7];
    const float* tW4 = (const float*)d_in[8];  const float* tb4 = (const float*)d_in[9];
    const float* tW5 = (const float*)d_in[10]; const float* tb5 = (const float*)d_in[11];
    const float* sW1 = (const float*)d_in[12]; const float* sb1 = (const float*)d_in[13];
    const float* sW2 = (const float*)d_in[14]; const float* sb2 = (const float*)d_in[15];
    const float* sW3 = (const float*)d_in[16]; const float* sb3 = (const float*)d_in[17];
    const float* sW4 = (const float*)d_in[18]; const float* sb4 = (const float*)d_in[19];
    const float* sW5 = (const float*)d_in[20]; const float* sb5 = (const float*)d_in[21];

    const int B = in_sizes[0] / DD;
    float* Y  = (float*)d_out;
    float* LD = Y + (size_t)B * DD;

    unsigned char* pw = (unsigned char*)d_ws;   // needs 12*9216 = 110,592 B
    hipLaunchKernelGGL(pack_frags, dim3(NL * 2), dim3(256), 0, stream,
                       tW1, tW2, tW3, tW4, tW5, sW1, sW2, sW3, sW4, sW5, pw);

    const int nwaves = (B + 31) / 32;
    const int blocks = (nwaves + 3) / 4;        // 4 waves (256 thr) per block
    hipLaunchKernelGGL(realnvp_mfma16p, dim3(blocks), dim3(256), 0, stream,
                       X, pw, tb1, tb2, tb3, tb4, tb5, sb1, sb2, sb3, sb4, sb5,
                       Y, LD, B);
}

// Round 20
// 68.164 us; speedup vs baseline: 1.1191x; 1.1191x over previous
//
#include <hip/hip_runtime.h>
#include <math.h>

#define NL 6
#define DD 128

typedef __bf16 bf16x8 __attribute__((ext_vector_type(8)));
typedef float  f32x4  __attribute__((ext_vector_type(4)));

// Frag file per (layer l, net p), base = (l*2+p)*NET_STRIDE (bytes):
//   [0,2048)    trunk A: 2 K-slices x (64 lanes x 16B)
//   [2048,5120) hidden A: 3 x (64 x 16B)   (slots e>=4 zero)
//   [5120,9216) head  A: 4 chunks x (64 x 16B) (slots e>=4 zero)
// Slot map (consistent in A and B, so internal order cancels):
//   slot(q,e) -> logical k = (e<4) ? 4q+e : 16+4q+(e-4)
#define NET_STRIDE 9216
#define OFF_HID    2048
#define OFF_HEAD   5120

static __device__ __forceinline__ unsigned cvt_pk_bf16(float lo, float hi){
    unsigned r;
    asm("v_cvt_pk_bf16_f32 %0, %1, %2" : "=v"(r) : "v"(lo), "v"(hi));
    return r;
}
static __device__ __forceinline__ f32x4 mfma(bf16x8 a, bf16x8 b, f32x4 c){
    return __builtin_amdgcn_mfma_f32_16x16x32_bf16(a, b, c, 0, 0, 0);
}
static __device__ __forceinline__ bf16x8 frag4(unsigned w0, unsigned w1, unsigned w2, unsigned w3){
    int4 v; v.x=(int)w0; v.y=(int)w1; v.z=(int)w2; v.w=(int)w3;
    return __builtin_bit_cast(bf16x8, v);
}
// relu(D regs) -> B-frag for K=16 layers. D feat = 4q+r matches B slot k=4q+e directly.
static __device__ __forceinline__ bf16x8 dreg_to_B(f32x4 d){
    unsigned w0 = cvt_pk_bf16(fmaxf(d[0],0.f), fmaxf(d[1],0.f));
    unsigned w1 = cvt_pk_bf16(fmaxf(d[2],0.f), fmaxf(d[3],0.f));
    return frag4(w0, w1, 0u, 0u);
}
static __device__ __forceinline__ bf16x8 load_frag(const unsigned char* nb, int off, int lane){
    return *(const bf16x8*)(nb + off + lane * 16);
}
// epilogue: y = (xp - t)*e^z with z = 2*rcp(e^{2s}+1)-1 = -tanh(s),
// e^z via deg-5 poly on [-1,1] (err ~5e-5). zacc accumulates z -> LD = +sum(z).
static __device__ __forceinline__ void epi(f32x4 tD, f32x4 sD,
                                           float4 &xa, float4 &xp, float &zacc){
    float xq[4] = {xp.x, xp.y, xp.z, xp.w};
    float nv[4];
    #pragma unroll
    for (int r = 0; r < 4; ++r){
        float u  = exp2f(sD[r] * 2.885390081777927f);      // e^{2s} (sat inf/0, safe)
        float rr = __builtin_amdgcn_rcpf(u + 1.f);
        float z  = fmaf(2.f, rr, -1.f);                    // -tanh(s) in [-1,1]
        float p  = fmaf(0.0086868208f, z, 0.0437939232f);  // e^z
        p = fmaf(p, z, 0.1664888732f);
        p = fmaf(p, z, 0.4991967560f);
        p = fmaf(p, z, 1.0000222901f);
        p = fmaf(p, z, 1.0000447786f);
        zacc += z;
        nv[r] = (xq[r] - tD[r]) * p;
    }
    xp = xa;
    xa = (float4){nv[0], nv[1], nv[2], nv[3]};
}

// ---------- pack kernel ----------
static __device__ __forceinline__ unsigned short f2bf_rne(float f){
    unsigned u = __float_as_uint(f);
    u += 0x7FFFu + ((u >> 16) & 1u);
    return (unsigned short)(u >> 16);
}

__global__ void pack_frags(
    const float* __restrict__ tW1, const float* __restrict__ tW2,
    const float* __restrict__ tW3, const float* __restrict__ tW4,
    const float* __restrict__ tW5,
    const float* __restrict__ sW1, const float* __restrict__ sW2,
    const float* __restrict__ sW3, const float* __restrict__ sW4,
    const float* __restrict__ sW5,
    unsigned char* __restrict__ pw)
{
    const int bx = blockIdx.x;           // = l*2 + p
    const int l = bx >> 1, p = bx & 1;
    const int aOff = (l & 1) ? 0 : 64;
    const int pOff = 64 - aOff;
    const float* W1 = p ? sW1 : tW1;
    const float* W2 = p ? sW2 : tW2;
    const float* W3 = p ? sW3 : tW3;
    const float* W4 = p ? sW4 : tW4;
    const float* W5 = p ? sW5 : tW5;
    unsigned char* base = pw + (size_t)bx * NET_STRIDE;

    for (int t = threadIdx.x; t < 576; t += blockDim.x){
        const int lane = t & 63, m = lane & 15, q = lane >> 4;
        unsigned short v[8];
        unsigned char* dst;
        if (t < 128){                    // trunk: full K=32 slices
            int slice = t >> 6;
            #pragma unroll
            for (int e = 0; e < 8; ++e){
                int sg = (e < 4) ? (4*q + e) : (16 + 4*q + (e - 4));
                v[e] = f2bf_rne(W1[l*2048 + (aOff + 32*slice + sg)*16 + m]);
            }
            dst = base + slice*1024 + lane*16;
        } else if (t < 320){             // hidden: K=16 in slots e<4, zeros above
            int hh = (t - 128) >> 6;
            const float* W = (hh == 0) ? W2 : (hh == 1) ? W3 : W4;
            #pragma unroll
            for (int e = 0; e < 8; ++e)
                v[e] = (e < 4) ? f2bf_rne(W[l*256 + (4*q + e)*16 + m]) : (unsigned short)0;
            dst = base + OFF_HID + hh*1024 + lane*16;
        } else {                         // head chunk c: passive feats pOff+16c+m
            int c = (t - 320) >> 6;
            #pragma unroll
            for (int e = 0; e < 8; ++e)
                v[e] = (e < 4) ? f2bf_rne(W5[l*2048 + (4*q + e)*128 + pOff + 16*c + m])
                               : (unsigned short)0;
            dst = base + OFF_HEAD + c*1024 + lane*16;
        }
        int4 o;
        o.x = (int)((unsigned)v[0] | ((unsigned)v[1] << 16));
        o.y = (int)((unsigned)v[2] | ((unsigned)v[3] << 16));
        o.z = (int)((unsigned)v[4] | ((unsigned)v[5] << 16));
        o.w = (int)((unsigned)v[6] | ((unsigned)v[7] << 16));
        *(int4*)dst = o;
    }
}

// ---------- main kernel (round-13 proven): 2 x 16-row tiles/wave ----------
__global__ __launch_bounds__(256, 4)
void realnvp_mfma16x2(const float* __restrict__ X, const unsigned char* __restrict__ PW,
    const float* __restrict__ tb1, const float* __restrict__ tb2,
    const float* __restrict__ tb3, const float* __restrict__ tb4,
    const float* __restrict__ tb5,
    const float* __restrict__ sb1, const float* __restrict__ sb2,
    const float* __restrict__ sb3, const float* __restrict__ sb4,
    const float* __restrict__ sb5,
    float* __restrict__ Y, float* __restrict__ LD, int B)
{
    __shared__ float4 xpl[8][256];       // passive halves, tile0 in [0:4), tile1 in [4:8)
    const int tid  = threadIdx.x;
    const int lane = tid & 63;
    const int wid  = blockIdx.x * 4 + (tid >> 6);
    const int q = lane >> 4, n = lane & 15;
    const int r0 = wid * 32 + n;
    const int r1 = r0 + 16;
    if (wid * 32 >= B) return;
    const int r0c = (r0 < B) ? r0 : (B - 1);
    const int r1c = (r1 < B) ? r1 : (B - 1);

    const float* x0 = X + (size_t)r0c * DD;
    const float* x1 = X + (size_t)r1c * DD;
    float4 xa0[4], xa1[4];
    #pragma unroll
    for (int j = 0; j < 4; ++j){
        const int off = 16*j + 4*q;
        xa0[j]          = *(const float4*)(x0 + off);
        xpl[j][tid]     = *(const float4*)(x0 + 64 + off);
        xa1[j]          = *(const float4*)(x1 + off);
        xpl[4 + j][tid] = *(const float4*)(x1 + 64 + off);
    }
    float zacc0 = 0.f, zacc1 = 0.f;

    #pragma unroll 1
    for (int step = 0; step < NL; ++step){
        const int l = NL - 1 - step;
        const int pOff = (l & 1) ? 64 : 0;
        const unsigned char* bt = PW + (size_t)(l * 2 + 0) * NET_STRIDE;
        const unsigned char* bs = bt + NET_STRIDE;

        // ---- trunk B-frags (per tile) ----
        bf16x8 B00 = frag4(cvt_pk_bf16(xa0[0].x, xa0[0].y), cvt_pk_bf16(xa0[0].z, xa0[0].w),
                           cvt_pk_bf16(xa0[1].x, xa0[1].y), cvt_pk_bf16(xa0[1].z, xa0[1].w));
        bf16x8 B01 = frag4(cvt_pk_bf16(xa0[2].x, xa0[2].y), cvt_pk_bf16(xa0[2].z, xa0[2].w),
                           cvt_pk_bf16(xa0[3].x, xa0[3].y), cvt_pk_bf16(xa0[3].z, xa0[3].w));
        bf16x8 B10 = frag4(cvt_pk_bf16(xa1[0].x, xa1[0].y), cvt_pk_bf16(xa1[0].z, xa1[0].w),
                           cvt_pk_bf16(xa1[1].x, xa1[1].y), cvt_pk_bf16(xa1[1].z, xa1[1].w));
        bf16x8 B11 = frag4(cvt_pk_bf16(xa1[2].x, xa1[2].y), cvt_pk_bf16(xa1[2].z, xa1[2].w),
                           cvt_pk_bf16(xa1[3].x, xa1[3].y), cvt_pk_bf16(xa1[3].z, xa1[3].w));

        // ---- trunk: K=64 as 2 x K32; A-frags + bias loaded once, used for both tiles ----
        f32x4 cbt = *(const f32x4*)(tb1 + l*16 + 4*q);
        f32x4 cbs = *(const f32x4*)(sb1 + l*16 + 4*q);
        bf16x8 A0t = load_frag(bt, 0, lane), A1t = load_frag(bt, 1024, lane);
        bf16x8 A0s = load_frag(bs, 0, lane), A1s = load_frag(bs, 1024, lane);
        f32x4 at0 = mfma(A0t, B00, cbt); at0 = mfma(A1t, B01, at0);
        f32x4 at1 = mfma(A0t, B10, cbt); at1 = mfma(A1t, B11, at1);
        f32x4 as0 = mfma(A0s, B00, cbs); as0 = mfma(A1s, B01, as0);
        f32x4 as1 = mfma(A0s, B10, cbs); as1 = mfma(A1s, B11, as1);

        // ---- 3 hidden 16x16 layers ----
        #pragma unroll
        for (int hh = 0; hh < 3; ++hh){
            const float* hbt = (hh == 0) ? tb2 : (hh == 1) ? tb3 : tb4;
            const float* hbs = (hh == 0) ? sb2 : (hh == 1) ? sb3 : sb4;
            f32x4 ct = *(const f32x4*)(hbt + l*16 + 4*q);
            f32x4 cs = *(const f32x4*)(hbs + l*16 + 4*q);
            bf16x8 At = load_frag(bt, OFF_HID + hh*1024, lane);
            bf16x8 As = load_frag(bs, OFF_HID + hh*1024, lane);
            at0 = mfma(At, dreg_to_B(at0), ct);
            at1 = mfma(At, dreg_to_B(at1), ct);
            as0 = mfma(As, dreg_to_B(as0), cs);
            as1 = mfma(As, dreg_to_B(as1), cs);
        }

        // ---- heads: 4 chunks of 16 passive feats, chunk-serial ----
        bf16x8 Bf_t0 = dreg_to_B(at0), Bf_t1 = dreg_to_B(at1);
        bf16x8 Bf_s0 = dreg_to_B(as0), Bf_s1 = dreg_to_B(as1);
        #pragma unroll
        for (int c = 0; c < 4; ++c){
            f32x4 ct = *(const f32x4*)(tb5 + l*128 + pOff + 16*c + 4*q);
            f32x4 cs = *(const f32x4*)(sb5 + l*128 + pOff + 16*c + 4*q);
            bf16x8 Aht = load_frag(bt, OFF_HEAD + c*1024, lane);
            bf16x8 Ahs = load_frag(bs, OFF_HEAD + c*1024, lane);
            f32x4 tD0 = mfma(Aht, Bf_t0, ct);
            f32x4 sD0 = mfma(Ahs, Bf_s0, cs);
            f32x4 tD1 = mfma(Aht, Bf_t1, ct);
            f32x4 sD1 = mfma(Ahs, Bf_s1, cs);

            float4 xp0 = xpl[c][tid];
            epi(tD0, sD0, xa0[c], xp0, zacc0);
            xpl[c][tid] = xp0;

            float4 xp1 = xpl[4 + c][tid];
            epi(tD1, sD1, xa1[c], xp1, zacc1);
            xpl[4 + c][tid] = xp1;
        }
    }

    // final: xa = feats [0,64), xpl = feats [64,128);  LD = +sum(z) = -sum(tanh s)
    if (r0 < B){
        float* y0 = Y + (size_t)r0 * DD;
        #pragma unroll
        for (int j = 0; j < 4; ++j){
            const int off = 16*j + 4*q;
            *(float4*)(y0 + off)      = xa0[j];
            *(float4*)(y0 + 64 + off) = xpl[j][tid];
        }
        float ls = zacc0;
        ls += __shfl_xor(ls, 16, 64);
        ls += __shfl_xor(ls, 32, 64);
        if (q == 0) LD[r0] = ls;
    }
    if (r1 < B){
        float* y1 = Y + (size_t)r1 * DD;
        #pragma unroll
        for (int j = 0; j < 4; ++j){
            const int off = 16*j + 4*q;
            *(float4*)(y1 + off)      = xa1[j];
            *(float4*)(y1 + 64 + off) = xpl[4 + j][tid];
        }
        float ls = zacc1;
        ls += __shfl_xor(ls, 16, 64);
        ls += __shfl_xor(ls, 32, 64);
        if (q == 0) LD[r1] = ls;
    }
}

extern "C" void kernel_launch(void* const* d_in, const int* in_sizes, int n_in,
                              void* d_out, int out_size, void* d_ws, size_t ws_size,
                              hipStream_t stream)
{
    const float* X   = (const float*)d_in[0];
    const float* tW1 = (const float*)d_in[2];  const float* tb1 = (const float*)d_in[3];
    const float* tW2 = (const float*)d_in[4];  const float* tb2 = (const float*)d_in[5];
    const float* tW3 = (const float*)d_in[6];  const float* tb3 = (const float*)d_in[7];
    const float* tW4 = (const float*)d_in[8];  const float* tb4 = (const float*)d_in[9];
    const float* tW5 = (const float*)d_in[10]; const float* tb5 = (const float*)d_in[11];
    const float* sW1 = (const float*)d_in[12]; const float* sb1 = (const float*)d_in[13];
    const float* sW2 = (const float*)d_in[14]; const float* sb2 = (const float*)d_in[15];
    const float* sW3 = (const float*)d_in[16]; const float* sb3 = (const float*)d_in[17];
    const float* sW4 = (const float*)d_in[18]; const float* sb4 = (const float*)d_in[19];
    const float* sW5 = (const float*)d_in[20]; const float* sb5 = (const float*)d_in[21];

    const int B = in_sizes[0] / DD;
    float* Y  = (float*)d_out;
    float* LD = Y + (size_t)B * DD;

    unsigned char* pw = (unsigned char*)d_ws;   // needs 12*9216 = 110,592 B
    hipLaunchKernelGGL(pack_frags, dim3(NL * 2), dim3(256), 0, stream,
                       tW1, tW2, tW3, tW4, tW5, sW1, sW2, sW3, sW4, sW5, pw);

    const int nwaves = (B + 31) / 32;
    const int blocks = (nwaves + 3) / 4;        // 4 waves (256 thr) per block
    hipLaunchKernelGGL(realnvp_mfma16x2, dim3(blocks), dim3(256), 0, stream,
                       X, pw, tb1, tb2, tb3, tb4, tb5, sb1, sb2, sb3, sb4, sb5,
                       Y, LD, B);
}